// Round 10
// baseline (2798.642 us; speedup 1.0000x reference)
//
#include <hip/hip_runtime.h>
#include <hip/hip_bf16.h>

typedef _Float16 f16;
typedef _Float16 f16v2 __attribute__((ext_vector_type(2)));
typedef _Float16 f16v4 __attribute__((ext_vector_type(4)));
typedef _Float16 f16v8 __attribute__((ext_vector_type(8)));

#define BB   2
#define LL   21
#define HH   512
#define WW   512
#define RR   20
#define NCH  84
#define HW   (HH*WW)
#define VSEG 64
#define NSTRIP 6

__device__ __forceinline__ float nrminv(int x, int y) {
    int cx = min(x + RR, WW - 1) - max(x - RR, 0) + 1;
    int cy = min(y + RR, HH - 1) - max(y - RR, 0) + 1;
    return 1.0f / (float)(cx * cy);
}

// ---- init-phase kernels (verified, unchanged) ------------------------------
__global__ __launch_bounds__(128) void vboxf_k(const float* __restrict__ src,
                                               float* __restrict__ dst) {
    int pp = blockIdx.y;
    int y0 = blockIdx.x * VSEG;
    const float* s = src + (size_t)pp * HW + threadIdx.x * 4;
    float* d = dst + (size_t)pp * HW + threadIdx.x * 4;
    float s0 = 0.f, s1 = 0.f, s2 = 0.f, s3 = 0.f;
    int lo = y0 - RR; if (lo < 0) lo = 0;
    int hi = y0 + RR;
    for (int yy = lo; yy <= hi; ++yy) {
        float4 v = *(const float4*)(s + (size_t)yy * WW);
        s0 += v.x; s1 += v.y; s2 += v.z; s3 += v.w;
    }
    { float4 o = {s0, s1, s2, s3}; *(float4*)(d + (size_t)y0 * WW) = o; }
    #pragma unroll 4
    for (int y = y0 + 1; y < y0 + VSEG; ++y) {
        int ya = y + RR, ys = y - RR - 1;
        if (ya < HH) {
            float4 v = *(const float4*)(s + (size_t)ya * WW);
            s0 += v.x; s1 += v.y; s2 += v.z; s3 += v.w;
        }
        if (ys >= 0) {
            float4 v = *(const float4*)(s + (size_t)ys * WW);
            s0 -= v.x; s1 -= v.y; s2 -= v.z; s3 -= v.w;
        }
        float4 o = {s0, s1, s2, s3};
        *(float4*)(d + (size_t)y * WW) = o;
    }
}

template <typename T, typename V4>
__device__ __forceinline__ void load_win16(const T* __restrict__ srow, int x0,
                                           float* __restrict__ raw) {
    #pragma unroll
    for (int c = 0; c < 15; ++c) {
        int st = x0 - 24 + 4 * c;
        if (st >= 0 && st < WW) {
            V4 v = *(const V4*)(srow + st);
            raw[4*c+0] = (float)v.x; raw[4*c+1] = (float)v.y;
            raw[4*c+2] = (float)v.z; raw[4*c+3] = (float)v.w;
        } else {
            raw[4*c+0] = 0.f; raw[4*c+1] = 0.f; raw[4*c+2] = 0.f; raw[4*c+3] = 0.f;
        }
    }
}
__device__ __forceinline__ void slide16(const float* __restrict__ raw,
                                        float* __restrict__ res) {
    float sum = 0.f;
    #pragma unroll
    for (int j = 4; j <= 44; ++j) sum += raw[j];
    res[0] = sum;
    #pragma unroll
    for (int k = 1; k < 16; ++k) { sum += raw[k+44] - raw[k+3]; res[k] = sum; }
}
__device__ __forceinline__ void slide8(const float* __restrict__ raw,
                                       float* __restrict__ res) {
    float sum = 0.f;
    #pragma unroll
    for (int j = 4; j <= 44; ++j) sum += raw[j];
    res[0] = sum;
    #pragma unroll
    for (int k = 1; k < 8; ++k) { sum += raw[k+44] - raw[k+3]; res[k] = sum; }
}

__global__ __launch_bounds__(256) void hboxf_k(const float* __restrict__ src,
                                               float* __restrict__ dst) {
    int pp = blockIdx.y;
    int row = blockIdx.x * 8 + (threadIdx.x >> 5);
    int x0 = (threadIdx.x & 31) << 4;
    const float* srow = src + (size_t)pp * HW + (size_t)row * WW;
    float raw[60], res[16];
    load_win16<float, float4>(srow, x0, raw);
    slide16(raw, res);
    float* drow = dst + (size_t)pp * HW + (size_t)row * WW + x0;
    #pragma unroll
    for (int g = 0; g < 4; ++g) {
        float4 o = {res[4*g], res[4*g+1], res[4*g+2], res[4*g+3]};
        *(float4*)(drow + 4*g) = o;
    }
}

__global__ __launch_bounds__(256) void prod_k(float* __restrict__ Pf,
                                              const float* __restrict__ Refs) {
    int idx = blockIdx.x * 256 + threadIdx.x;
    int b = idx >> 18, pix = idx & (HW - 1);
    float I0 = Refs[((size_t)b * 3 + 0) * HW + pix];
    float I1 = Refs[((size_t)b * 3 + 1) * HW + pix];
    float I2 = Refs[((size_t)b * 3 + 2) * HW + pix];
    size_t base = (size_t)b * 9 * HW + pix;
    Pf[base + (size_t)0 * HW] = I0;
    Pf[base + (size_t)1 * HW] = I1;
    Pf[base + (size_t)2 * HW] = I2;
    Pf[base + (size_t)3 * HW] = I0 * I0;
    Pf[base + (size_t)4 * HW] = I0 * I1;
    Pf[base + (size_t)5 * HW] = I0 * I2;
    Pf[base + (size_t)6 * HW] = I1 * I1;
    Pf[base + (size_t)7 * HW] = I1 * I2;
    Pf[base + (size_t)8 * HW] = I2 * I2;
}

__global__ __launch_bounds__(256) void prep_k(const float* __restrict__ Bf,
                                              float* __restrict__ Ainv, float* __restrict__ mI,
                                              const float* __restrict__ epsp) {
    int idx = blockIdx.x * 256 + threadIdx.x;
    int b = idx >> 18, pix = idx & (HW - 1);
    int x = pix & (WW - 1), y = pix >> 9;
    float nrm = nrminv(x, y);
    float eps = epsp[0];
    size_t base = (size_t)b * 9 * HW + pix;
    float m0 = Bf[base + (size_t)0 * HW] * nrm;
    float m1 = Bf[base + (size_t)1 * HW] * nrm;
    float m2 = Bf[base + (size_t)2 * HW] * nrm;
    float v00 = Bf[base + (size_t)3 * HW] * nrm - m0 * m0 + eps;
    float v01 = Bf[base + (size_t)4 * HW] * nrm - m0 * m1;
    float v02 = Bf[base + (size_t)5 * HW] * nrm - m0 * m2;
    float v11 = Bf[base + (size_t)6 * HW] * nrm - m1 * m1 + eps;
    float v12 = Bf[base + (size_t)7 * HW] * nrm - m1 * m2;
    float v22 = Bf[base + (size_t)8 * HW] * nrm - m2 * m2 + eps;
    float c00 = v11 * v22 - v12 * v12;
    float c01 = v02 * v12 - v01 * v22;
    float c02 = v01 * v12 - v02 * v11;
    float c11 = v00 * v22 - v02 * v02;
    float c12 = v01 * v02 - v00 * v12;
    float c22 = v00 * v11 - v01 * v01;
    float det = v00 * c00 + v01 * c01 + v02 * c02;
    float id = 1.0f / det;
    size_t ab = (size_t)b * 6 * HW + pix;
    Ainv[ab + (size_t)0 * HW] = c00 * id;
    Ainv[ab + (size_t)1 * HW] = c01 * id;
    Ainv[ab + (size_t)2 * HW] = c02 * id;
    Ainv[ab + (size_t)3 * HW] = c11 * id;
    Ainv[ab + (size_t)4 * HW] = c12 * id;
    Ainv[ab + (size_t)5 * HW] = c22 * id;
    size_t mb = (size_t)b * 3 * HW + pix;
    mI[mb]                  = m0;
    mI[mb + (size_t)HW]     = m1;
    mI[mb + (size_t)2 * HW] = m2;
}

// ---- Refs fp32 -> f16 copy (one-time) --------------------------------------
__global__ __launch_bounds__(256) void refs16_k(f16* __restrict__ R16,
                                                const float* __restrict__ Refs) {
    int i = blockIdx.x * 256 + threadIdx.x;   // grid covers BB*3*HW
    R16[i] = (f16)Refs[i];
}

// ---- mega kernel: p -> box(p,Ip) -> solve -> box(b,a) -> q  (per b,l,strip) -
// waves 0-3: column-owners (ch = t&3, colgroup = t>>2): va_lead/va_trail/vq
// waves 4-7: solvers: 8 staged rows (4 lead + 4 trail) x 32 threads x 16 px
// LDS: vs (vertical sums), ab (solved b,a rows); pad-col = img-col + 24.
__device__ __forceinline__ void acc8m(const f16* __restrict__ prow,
                                      const f16* __restrict__ rrow, bool mul,
                                      float sgn, float* __restrict__ va) {
    f16v8 v = *(const f16v8*)(prow);
    if (mul) {
        f16v8 rv = *(const f16v8*)(rrow);
        #pragma unroll
        for (int i = 0; i < 8; ++i) va[i] += sgn * (float)v[i] * (float)rv[i];
    } else {
        #pragma unroll
        for (int i = 0; i < 8; ++i) va[i] += sgn * (float)v[i];
    }
}

__global__ __launch_bounds__(512, 2) void mega_k(const f16* __restrict__ P,
                                                 f16* __restrict__ Q,
                                                 const float* __restrict__ Ainv,
                                                 const float* __restrict__ mI,
                                                 const f16* __restrict__ R16) {
    __shared__ f16 vs[8][4][576];   // 36,864 B
    __shared__ f16 ab[8][4][576];   // 36,864 B
    int strip = blockIdx.x;
    int bl = blockIdx.y;
    int b = bl / LL, l = bl - b * LL;
    int y0 = (strip * HH) / NSTRIP;
    int yend = ((strip + 1) * HH) / NSTRIP;
    int s1lo = y0 - 20; if (s1lo < 0) s1lo = 0;       // first lead row
    int s1hi = yend + 19; if (s1hi > HH - 1) s1hi = HH - 1;  // last lead row
    int tmax = yend - 22;                              // last trail row
    int t = threadIdx.x;
    bool owner = (t < 256);

    // zero pads of vs (t<256) and ab (t>=256): chunks {0,1,2,67..71} per row,ch
    {
        int u = t & 255;
        int rr = u >> 5, rem = u & 31, cc = rem >> 2, cp = rem & 3;
        int chunk = (cc < 3) ? cc : (64 + cc);
        f16v8 z = {};
        if (t < 256) *(f16v8*)(&vs[rr][cp][8 * chunk]) = z;
        else         *(f16v8*)(&ab[rr][cp][8 * chunk]) = z;
    }

    // col-owner setup
    int ch = t & 3, g8 = (t >> 2) & 63;
    int cx = g8 * 8;
    const f16* pP = P + ((size_t)(b * NCH) + l) * HW + cx;
    int rch = (ch == 0) ? 0 : ch - 1;
    const f16* pR = R16 + ((size_t)b * 3 + rch) * HW + cx;
    bool mul = (ch != 0);
    float vl[8], vt[8], vq[8];
    #pragma unroll
    for (int i = 0; i < 8; ++i) { vl[i] = 0.f; vt[i] = 0.f; vq[i] = 0.f; }

    // solver setup
    int u2 = t - 256;
    int rs = u2 >> 5;              // 0..7 (0-3 lead, 4-7 trail)
    int x0 = (u2 & 31) << 4;       // 16 px

    if (owner) {
        // va_lead invariant entering row s1lo: sum p rows [max(0,s1lo-21), s1lo+19]
        int a0 = s1lo - 21; if (a0 < 0) a0 = 0;
        for (int yy = a0; yy <= s1lo + 19; ++yy)
            acc8m(pP + (size_t)yy * WW, pR + (size_t)yy * WW, mul, 1.f, vl);
        // va_trail invariant entering row s1lo-41: rows [max(0,s1lo-62), s1lo-22]
        int b0 = s1lo - 62; if (b0 < 0) b0 = 0;
        for (int yy = b0; yy <= s1lo - 22; ++yy)
            acc8m(pP + (size_t)yy * WW, pR + (size_t)yy * WW, mul, 1.f, vt);
        // A(0): produce group-0 vsum rows
        #pragma unroll
        for (int k = 0; k < 4; ++k) {
            int r = s1lo + k;
            if (r <= s1hi) {
                if (r + 20 < HH) acc8m(pP + (size_t)(r + 20) * WW, pR + (size_t)(r + 20) * WW, mul, 1.f, vl);
                if (r - 21 >= 0) acc8m(pP + (size_t)(r - 21) * WW, pR + (size_t)(r - 21) * WW, mul, -1.f, vl);
                f16v8 o;
                #pragma unroll
                for (int i = 0; i < 8; ++i) o[i] = (f16)vl[i];
                *(f16v8*)(&vs[k][ch][24 + cx]) = o;
            }
            int rt = r - 41;
            if (rt <= tmax) {
                int ra = rt + 20;
                if (ra >= 0 && ra < HH) acc8m(pP + (size_t)ra * WW, pR + (size_t)ra * WW, mul, 1.f, vt);
                if (rt - 21 >= 0) acc8m(pP + (size_t)(rt - 21) * WW, pR + (size_t)(rt - 21) * WW, mul, -1.f, vt);
                if (rt >= s1lo) {
                    f16v8 o;
                    #pragma unroll
                    for (int i = 0; i < 8; ++i) o[i] = (f16)vt[i];
                    *(f16v8*)(&vs[4 + k][ch][24 + cx]) = o;
                }
            }
        }
    }
    __syncthreads();

    int niter = (yend + 20) - s1lo;
    int ng = (niter + 3) >> 2;
    for (int gg = 0; gg < ng; ++gg) {
        int rg = s1lo + 4 * gg;

        // ---- B: solvers: vsum -> slide16 -> 3x3 solve -> ab rows ----
        if (!owner) {
            int r_abs; bool valid;
            if (rs < 4) { r_abs = rg + rs; valid = (r_abs <= s1hi); }
            else { r_abs = rg + rs - 45; valid = (r_abs >= s1lo && r_abs <= tmax); }
            if (valid) {
                float res[4][16];
                #pragma unroll
                for (int c = 0; c < 4; ++c) {
                    float raw[64];
                    #pragma unroll
                    for (int cc = 0; cc < 8; ++cc) {
                        f16v8 v = *(const f16v8*)(&vs[rs][c][x0 + 8 * cc]);
                        #pragma unroll
                        for (int e = 0; e < 8; ++e) raw[8 * cc + e] = (float)v[e];
                    }
                    slide16(raw, res[c]);
                }
                size_t pixb = (size_t)r_abs * WW + x0;
                size_t abb = (size_t)b * 6 * HW + pixb;
                size_t mb = (size_t)b * 3 * HW + pixb;
                #pragma unroll
                for (int gq = 0; gq < 4; ++gq) {
                    float iv[6][4], mi[3][4];
                    #pragma unroll
                    for (int j = 0; j < 6; ++j) {
                        float4 v = *(const float4*)(Ainv + abb + (size_t)j * HW + 4 * gq);
                        iv[j][0] = v.x; iv[j][1] = v.y; iv[j][2] = v.z; iv[j][3] = v.w;
                    }
                    #pragma unroll
                    for (int j = 0; j < 3; ++j) {
                        float4 v = *(const float4*)(mI + mb + (size_t)j * HW + 4 * gq);
                        mi[j][0] = v.x; mi[j][1] = v.y; mi[j][2] = v.z; mi[j][3] = v.w;
                    }
                    #pragma unroll
                    for (int e = 0; e < 4; ++e) {
                        int k = 4 * gq + e;
                        float nrm = nrminv(x0 + k, r_abs);
                        float mp   = res[0][k] * nrm;
                        float cov0 = res[1][k] * nrm - mi[0][e] * mp;
                        float cov1 = res[2][k] * nrm - mi[1][e] * mp;
                        float cov2 = res[3][k] * nrm - mi[2][e] * mp;
                        float a0 = iv[0][e] * cov0 + iv[1][e] * cov1 + iv[2][e] * cov2;
                        float a1 = iv[1][e] * cov0 + iv[3][e] * cov1 + iv[4][e] * cov2;
                        float a2 = iv[2][e] * cov0 + iv[4][e] * cov1 + iv[5][e] * cov2;
                        float bb = mp - (a0 * mi[0][e] + a1 * mi[1][e] + a2 * mi[2][e]);
                        res[0][k] = bb; res[1][k] = a0; res[2][k] = a1; res[3][k] = a2;
                    }
                }
                #pragma unroll
                for (int c = 0; c < 4; ++c) {
                    f16v8 o0, o1;
                    #pragma unroll
                    for (int e = 0; e < 8; ++e) { o0[e] = (f16)res[c][e]; o1[e] = (f16)res[c][8 + e]; }
                    *(f16v8*)(&ab[rs][c][24 + x0]) = o0;
                    *(f16v8*)(&ab[rs][c][24 + x0 + 8]) = o1;
                }
            }
        }
        __syncthreads();

        // ---- D(gg): owners: H slides, vq update, emit; then A(gg+1) ----
        if (owner) {
            #pragma unroll
            for (int k = 0; k < 4; ++k) {
                int r = rg + k;
                int pos = r - 20;
                if (pos >= yend) break;
                if (r <= s1hi) {
                    float raw[56], H[8];
                    #pragma unroll
                    for (int cc = 0; cc < 7; ++cc) {
                        f16v8 v = *(const f16v8*)(&ab[k][ch][cx + 8 * cc]);
                        #pragma unroll
                        for (int e = 0; e < 8; ++e) raw[8 * cc + e] = (float)v[e];
                    }
                    slide8(raw, H);
                    #pragma unroll
                    for (int i = 0; i < 8; ++i) vq[i] += H[i];
                }
                if (r - 41 >= s1lo) {
                    float raw[56], H[8];
                    #pragma unroll
                    for (int cc = 0; cc < 7; ++cc) {
                        f16v8 v = *(const f16v8*)(&ab[4 + k][ch][cx + 8 * cc]);
                        #pragma unroll
                        for (int e = 0; e < 8; ++e) raw[8 * cc + e] = (float)v[e];
                    }
                    slide8(raw, H);
                    #pragma unroll
                    for (int i = 0; i < 8; ++i) vq[i] -= H[i];
                }
                if (pos >= y0) {
                    float term[8];
                    if (mul) {
                        f16v8 I = *(const f16v8*)(pR + (size_t)pos * WW);
                        #pragma unroll
                        for (int i = 0; i < 8; ++i) term[i] = vq[i] * (float)I[i];
                    } else {
                        #pragma unroll
                        for (int i = 0; i < 8; ++i) term[i] = vq[i];
                    }
                    #pragma unroll
                    for (int i = 0; i < 8; ++i) {
                        term[i] += __shfl_xor(term[i], 1);
                        term[i] += __shfl_xor(term[i], 2);
                    }
                    if (ch == 0) {
                        f16v8 o;
                        #pragma unroll
                        for (int i = 0; i < 8; ++i)
                            o[i] = (f16)(term[i] * nrminv(cx + i, pos));
                        *(f16v8*)(Q + ((size_t)(b * LL) + l) * HW + (size_t)pos * WW + cx) = o;
                    }
                }
            }
            if (gg + 1 < ng) {
                int rg2 = rg + 4;
                #pragma unroll
                for (int k = 0; k < 4; ++k) {
                    int r = rg2 + k;
                    if (r <= s1hi) {
                        if (r + 20 < HH) acc8m(pP + (size_t)(r + 20) * WW, pR + (size_t)(r + 20) * WW, mul, 1.f, vl);
                        if (r - 21 >= 0) acc8m(pP + (size_t)(r - 21) * WW, pR + (size_t)(r - 21) * WW, mul, -1.f, vl);
                        f16v8 o;
                        #pragma unroll
                        for (int i = 0; i < 8; ++i) o[i] = (f16)vl[i];
                        *(f16v8*)(&vs[k][ch][24 + cx]) = o;
                    }
                    int rt = r - 41;
                    if (rt <= tmax) {
                        int ra = rt + 20;
                        if (ra >= 0 && ra < HH) acc8m(pP + (size_t)ra * WW, pR + (size_t)ra * WW, mul, 1.f, vt);
                        if (rt - 21 >= 0) acc8m(pP + (size_t)(rt - 21) * WW, pR + (size_t)(rt - 21) * WW, mul, -1.f, vt);
                        if (rt >= s1lo) {
                            f16v8 o;
                            #pragma unroll
                            for (int i = 0; i < 8; ++i) o[i] = (f16)vt[i];
                            *(f16v8*)(&vs[4 + k][ch][24 + cx]) = o;
                        }
                    }
                }
            }
        }
        __syncthreads();
    }
}

// ---- fused: E=E0+q, Q=softmax(-E), p=W.Q (2 px/thread) ---------------------
__global__ __launch_bounds__(256) void e_k(const f16* __restrict__ Q,
                                           f16* __restrict__ pout,
                                           const float* __restrict__ E0,
                                           const float* __restrict__ Wf,
                                           float* __restrict__ out, int mode) {
    int idx = blockIdx.x * 256 + threadIdx.x;
    int b = idx >> 17;
    int pix = (idx & (HW / 2 - 1)) * 2;
    size_t base  = (size_t)b * NCH * HW + pix;
    size_t ebase = (size_t)b * LL * HW + pix;
    float Ev0[LL], Ev1[LL];
    float m0 = -1e30f, m1 = -1e30f;
    #pragma unroll
    for (int l = 0; l < LL; ++l) {
        float2 e0 = *(const float2*)(E0 + ebase + (size_t)l * HW);
        float v0 = e0.x, v1 = e0.y;
        if (mode != 0) {
            f16v2 qv = *(const f16v2*)(Q + ebase + (size_t)l * HW);
            v0 += (float)qv.x; v1 += (float)qv.y;
        }
        Ev0[l] = -v0; Ev1[l] = -v1;
        m0 = fmaxf(m0, Ev0[l]); m1 = fmaxf(m1, Ev1[l]);
    }
    float s0 = 0.f, s1 = 0.f;
    #pragma unroll
    for (int l = 0; l < LL; ++l) {
        Ev0[l] = __expf(Ev0[l] - m0); s0 += Ev0[l];
        Ev1[l] = __expf(Ev1[l] - m1); s1 += Ev1[l];
    }
    float i0 = 1.0f / s0, i1 = 1.0f / s1;
    if (mode == 2) {
        #pragma unroll
        for (int l = 0; l < LL; ++l) {
            float2 o; o.x = Ev0[l] * i0; o.y = Ev1[l] * i1;
            *(float2*)(out + ebase + (size_t)l * HW) = o;
        }
    } else {
        #pragma unroll
        for (int l = 0; l < LL; ++l) { Ev0[l] *= i0; Ev1[l] *= i1; }
        #pragma unroll
        for (int l = 0; l < LL; ++l) {
            float p0 = 0.f, p1 = 0.f;
            #pragma unroll
            for (int m = 0; m < LL; ++m) {
                float w = Wf[l * LL + m];
                p0 += w * Ev0[m]; p1 += w * Ev1[m];
            }
            f16v2 o;
            o.x = (f16)p0; o.y = (f16)p1;
            *(f16v2*)(pout + base + (size_t)l * HW) = o;
        }
    }
}

// ---- host ------------------------------------------------------------------
extern "C" void kernel_launch(void* const* d_in, const int* in_sizes, int n_in,
                              void* d_out, int out_size, void* d_ws, size_t ws_size,
                              hipStream_t stream) {
    const float* E0   = (const float*)d_in[0];
    const float* Refs = (const float*)d_in[1];
    const float* Wmu  = (const float*)d_in[2];
    const float* epsp = (const float*)d_in[3];
    float* out = (float*)d_out;

    size_t Ub = (size_t)BB * NCH * HW * 2;   // 84 MB
    size_t Ab = (size_t)BB * 6 * HW * 4;
    size_t Mb = (size_t)BB * 3 * HW * 4;
    char* ws = (char*)d_ws;
    f16*   U    = (f16*)ws;                  // loop: p planes (f16, 21/b used)
    f16*   R16  = (f16*)(ws + Ub);           // loop: f16 Refs copy (3 MB)
    float* Ainv = (float*)(ws + 2 * Ub);
    float* mI   = (float*)(ws + 2 * Ub + Ab);
    f16*   Qb   = (f16*)(ws + 2 * Ub + Ab + Mb);
    float* Uf   = (float*)U;                 // init fp32 scratch alias
    float* Vf   = (float*)R16;               // init fp32 scratch alias

    int nblk = (BB * HW) / 256;
    prod_k<<<nblk, 256, 0, stream>>>(Uf, Refs);
    vboxf_k<<<dim3(HH / VSEG, BB * 9), 128, 0, stream>>>(Uf, Vf);
    hboxf_k<<<dim3(HH / 8, BB * 9), 256, 0, stream>>>(Vf, Uf);
    prep_k<<<nblk, 256, 0, stream>>>(Uf, Ainv, mI, epsp);
    refs16_k<<<(BB * 3 * HW) / 256, 256, 0, stream>>>(R16, Refs);
    e_k<<<(BB * HW / 2) / 256, 256, 0, stream>>>(Qb, U, E0, Wmu, out, 0);

    for (int t = 1; t <= 5; ++t) {
        mega_k<<<dim3(NSTRIP, BB * LL), 512, 0, stream>>>(U, Qb, Ainv, mI, R16);
        e_k<<<(BB * HW / 2) / 256, 256, 0, stream>>>(Qb, U, E0, Wmu, out,
                                                     t == 5 ? 2 : 1);
    }
}

// Round 11
// 1170.828 us; speedup vs baseline: 2.3903x; 2.3903x over previous
//
#include <hip/hip_runtime.h>
#include <hip/hip_bf16.h>

typedef _Float16 f16;
typedef _Float16 f16v2 __attribute__((ext_vector_type(2)));
typedef _Float16 f16v4 __attribute__((ext_vector_type(4)));
typedef _Float16 f16v8 __attribute__((ext_vector_type(8)));

#define BB   2
#define LL   21
#define HH   512
#define WW   512
#define RR   20
#define NCH  84            // planes per batch: p(21), Ic*p(63); later b,a
#define HW   (HH*WW)
#define VSEG 64            // rows per strip, fp32 init vbox

// fused-kernel LDS ring geometry (f32 vertical sums, XOR-swizzled; round-4 verified)
#define WROW 576           // padded row: x_s in [0,576): 24 left pad, 512 data, 40 right pad
#define RSTR 2320          // ring-row stride in words: 4*576 + 16 (rotates banks per row)
#define NSTRIP 6
#define NGRP 11            // ceil(max strip rows (86) / 8)

__device__ __forceinline__ float nrminv(int x, int y) {
    int cx = min(x + RR, WW - 1) - max(x - RR, 0) + 1;
    int cy = min(y + RR, HH - 1) - max(y - RR, 0) + 1;
    return 1.0f / (float)(cx * cy);
}

// involution on word indices; consistent for aligned float4 (swz(w+i)=swz(w)+i, i<4, w%4==0)
__device__ __forceinline__ int swz(int w) { return w ^ ((w >> 3) & 0x1C); }

// ---- vertical box fp32 (init only): 4 cols/thread --------------------------
__global__ __launch_bounds__(128) void vboxf_k(const float* __restrict__ src,
                                               float* __restrict__ dst) {
    int pp = blockIdx.y;
    int y0 = blockIdx.x * VSEG;
    const float* s = src + (size_t)pp * HW + threadIdx.x * 4;
    float* d = dst + (size_t)pp * HW + threadIdx.x * 4;
    float s0 = 0.f, s1 = 0.f, s2 = 0.f, s3 = 0.f;
    int lo = y0 - RR; if (lo < 0) lo = 0;
    int hi = y0 + RR;
    for (int yy = lo; yy <= hi; ++yy) {
        float4 v = *(const float4*)(s + (size_t)yy * WW);
        s0 += v.x; s1 += v.y; s2 += v.z; s3 += v.w;
    }
    { float4 o = {s0, s1, s2, s3}; *(float4*)(d + (size_t)y0 * WW) = o; }
    #pragma unroll 4
    for (int y = y0 + 1; y < y0 + VSEG; ++y) {
        int ya = y + RR, ys = y - RR - 1;
        if (ya < HH) {
            float4 v = *(const float4*)(s + (size_t)ya * WW);
            s0 += v.x; s1 += v.y; s2 += v.z; s3 += v.w;
        }
        if (ys >= 0) {
            float4 v = *(const float4*)(s + (size_t)ys * WW);
            s0 -= v.x; s1 -= v.y; s2 -= v.z; s3 -= v.w;
        }
        float4 o = {s0, s1, s2, s3};
        *(float4*)(d + (size_t)y * WW) = o;
    }
}

// ---- horizontal window helpers ---------------------------------------------
template <typename T, typename V4>
__device__ __forceinline__ void load_win16(const T* __restrict__ srow, int x0,
                                           float* __restrict__ raw) {
    #pragma unroll
    for (int c = 0; c < 15; ++c) {
        int st = x0 - 24 + 4 * c;
        if (st >= 0 && st < WW) {
            V4 v = *(const V4*)(srow + st);
            raw[4*c+0] = (float)v.x; raw[4*c+1] = (float)v.y;
            raw[4*c+2] = (float)v.z; raw[4*c+3] = (float)v.w;
        } else {
            raw[4*c+0] = 0.f; raw[4*c+1] = 0.f; raw[4*c+2] = 0.f; raw[4*c+3] = 0.f;
        }
    }
}
__device__ __forceinline__ void slide16(const float* __restrict__ raw,
                                        float* __restrict__ res) {
    float sum = 0.f;
    #pragma unroll
    for (int j = 4; j <= 44; ++j) sum += raw[j];   // [x0-20, x0+20]
    res[0] = sum;
    #pragma unroll
    for (int k = 1; k < 16; ++k) { sum += raw[k+44] - raw[k+3]; res[k] = sum; }
}

// ---- plain horizontal box (init, fp32): 16 px/thread -----------------------
__global__ __launch_bounds__(256) void hboxf_k(const float* __restrict__ src,
                                               float* __restrict__ dst) {
    int pp = blockIdx.y;
    int row = blockIdx.x * 8 + (threadIdx.x >> 5);
    int x0 = (threadIdx.x & 31) << 4;
    const float* srow = src + (size_t)pp * HW + (size_t)row * WW;
    float raw[60], res[16];
    load_win16<float, float4>(srow, x0, raw);
    slide16(raw, res);
    float* drow = dst + (size_t)pp * HW + (size_t)row * WW + x0;
    #pragma unroll
    for (int g = 0; g < 4; ++g) {
        float4 o = {res[4*g], res[4*g+1], res[4*g+2], res[4*g+3]};
        *(float4*)(drow + 4*g) = o;
    }
}

// ---- fused 2D box: producer (vertical running sums -> f32 LDS ring) --------
// BATCHED: all 16 independent row-loads of a group issue first, then the
// serial running-sum adds. Breaks the load->add->load latency chain that
// capped round-4 at VALUBusy 19% / 2.1 TB/s.
__device__ __forceinline__ void produce8(const f16* __restrict__ pu,
                                         float* __restrict__ ldsrow0,
                                         float* __restrict__ va,
                                         int gy, int yend, int buf,
                                         int ws0, int ws1) {
    f16v8 ra[8], rb[8];
    #pragma unroll
    for (int k = 0; k < 8; ++k) {
        int y = gy + k;
        if (y < yend) {
            int ya = y + RR;
            if (ya < HH) ra[k] = *(const f16v8*)(pu + (size_t)ya * WW);
            int yb = y - RR - 1;
            if (yb >= 0) rb[k] = *(const f16v8*)(pu + (size_t)yb * WW);
        }
    }
    #pragma unroll
    for (int k = 0; k < 8; ++k) {
        int y = gy + k;
        if (y < yend) {
            int ya = y + RR;
            if (ya < HH) {
                #pragma unroll
                for (int i = 0; i < 8; ++i) va[i] += (float)ra[k][i];
            }
            int yb = y - RR - 1;
            if (yb >= 0) {
                #pragma unroll
                for (int i = 0; i < 8; ++i) va[i] -= (float)rb[k][i];
            }
            float* dst = ldsrow0 + (size_t)(buf * 8 + k) * RSTR;
            float4 a = {va[0], va[1], va[2], va[3]};
            float4 b4 = {va[4], va[5], va[6], va[7]};
            *(float4*)(dst + ws0) = a;
            *(float4*)(dst + ws1) = b4;
        }
    }
}

// batched warm-up: accumulate rows [lo, hi] into va, loads batched 8 at a time
__device__ __forceinline__ void warmup(const f16* __restrict__ pu,
                                       float* __restrict__ va, int lo, int hi) {
    for (int y0c = lo; y0c <= hi; y0c += 8) {
        f16v8 r[8];
        #pragma unroll
        for (int k = 0; k < 8; ++k)
            if (y0c + k <= hi) r[k] = *(const f16v8*)(pu + (size_t)(y0c + k) * WW);
        #pragma unroll
        for (int k = 0; k < 8; ++k)
            if (y0c + k <= hi) {
                #pragma unroll
                for (int i = 0; i < 8; ++i) va[i] += (float)r[k][i];
            }
    }
}

// consumer raw-window load from swizzled LDS ring row
__device__ __forceinline__ void load_raw_lds(const float* __restrict__ base,
                                             int x0, float* __restrict__ raw) {
    #pragma unroll
    for (int k = 0; k < 16; ++k) {
        int w = x0 + 4 * k;
        float4 v = *(const float4*)(base + swz(w));
        raw[4*k+0] = v.x; raw[4*k+1] = v.y; raw[4*k+2] = v.z; raw[4*k+3] = v.w;
    }
}

// zero the pad columns (x_s in [0,24) and [536,576)) of all 16 ring rows x 4 ch
__device__ __forceinline__ void zero_pads(float* __restrict__ lds) {
    for (int p = threadIdx.x; p < 16 * 4 * 64; p += 512) {
        int ringrow = p >> 8;
        int rem = p & 255;
        int chp = rem >> 6, j = rem & 63;
        int w = (j < 24) ? j : (512 + j);
        lds[(size_t)ringrow * RSTR + chp * WROW + swz(w)] = 0.f;
    }
}

// ---- fused: vertical box + horizontal box + 3x3 solve  (U -> V as b,a) -----
__global__ __launch_bounds__(512, 2) void fused_solve_k(const f16* __restrict__ U,
                                                        f16* __restrict__ V,
                                                        const float* __restrict__ Ainv,
                                                        const float* __restrict__ mI) {
    __shared__ float lds[16 * RSTR];     // 145 KB
    int bl = blockIdx.y;
    int b = bl / LL, l = bl - b * LL;
    int strip = blockIdx.x;
    int y0s = (strip * HH) / NSTRIP;
    int yend = ((strip + 1) * HH) / NSTRIP;
    bool prod = (threadIdx.x < 256);

    int pch = threadIdx.x >> 6;          // producer channel 0..3
    int cx = (threadIdx.x & 63) * 8;
    int chsel = (pch == 0) ? l : (LL + (pch - 1) * LL + l);
    const f16* pu = U + (size_t)(b * NCH + chsel) * HW + cx;
    float* ldsrow0 = lds + pch * WROW;
    int ws0 = swz(cx + 24);
    int ws1 = swz(cx + 28);
    float va[8];
    #pragma unroll
    for (int i = 0; i < 8; ++i) va[i] = 0.f;

    zero_pads(lds);

    if (prod) {
        int lo = y0s - RR - 1; if (lo < 0) lo = 0;
        warmup(pu, va, lo, y0s + RR - 1);
        produce8(pu, ldsrow0, va, y0s, yend, 0, ws0, ws1);
    }
    __syncthreads();

    int u = threadIdx.x - 256;
    int r = u >> 5, i = u & 31;          // consumer: row slot, px group
    int x0 = i << 4;

    for (int g = 1; g <= NGRP; ++g) {
        if (prod) {
            if (g < NGRP) produce8(pu, ldsrow0, va, y0s + g * 8, yend, g & 1, ws0, ws1);
        } else {
            int gc = g - 1;
            int row = y0s + gc * 8 + r;
            if (row < yend) {
                float res[4][16];
                const float* rbase = lds + (size_t)((gc & 1) * 8 + r) * RSTR;
                #pragma unroll
                for (int c = 0; c < 4; ++c) {
                    float raw[64];
                    load_raw_lds(rbase + c * WROW, x0, raw);
                    slide16(raw, res[c]);
                }
                size_t pixb = (size_t)row * WW + x0;
                size_t ab = (size_t)b * 6 * HW + pixb;
                size_t mb = (size_t)b * 3 * HW + pixb;
                #pragma unroll
                for (int gq = 0; gq < 4; ++gq) {
                    float iv[6][4], mi[3][4];
                    #pragma unroll
                    for (int j = 0; j < 6; ++j) {
                        float4 v = *(const float4*)(Ainv + ab + (size_t)j * HW + 4 * gq);
                        iv[j][0] = v.x; iv[j][1] = v.y; iv[j][2] = v.z; iv[j][3] = v.w;
                    }
                    #pragma unroll
                    for (int j = 0; j < 3; ++j) {
                        float4 v = *(const float4*)(mI + mb + (size_t)j * HW + 4 * gq);
                        mi[j][0] = v.x; mi[j][1] = v.y; mi[j][2] = v.z; mi[j][3] = v.w;
                    }
                    #pragma unroll
                    for (int e = 0; e < 4; ++e) {
                        int k = 4 * gq + e;
                        float nrm = nrminv(x0 + k, row);
                        float mp   = res[0][k] * nrm;
                        float cov0 = res[1][k] * nrm - mi[0][e] * mp;
                        float cov1 = res[2][k] * nrm - mi[1][e] * mp;
                        float cov2 = res[3][k] * nrm - mi[2][e] * mp;
                        float a0 = iv[0][e] * cov0 + iv[1][e] * cov1 + iv[2][e] * cov2;
                        float a1 = iv[1][e] * cov0 + iv[3][e] * cov1 + iv[4][e] * cov2;
                        float a2 = iv[2][e] * cov0 + iv[4][e] * cov1 + iv[5][e] * cov2;
                        float bb = mp - (a0 * mi[0][e] + a1 * mi[1][e] + a2 * mi[2][e]);
                        res[0][k] = bb; res[1][k] = a0; res[2][k] = a1; res[3][k] = a2;
                    }
                }
                #pragma unroll
                for (int c = 0; c < 4; ++c) {
                    int chx = (c == 0) ? l : (LL + (c - 1) * LL + l);
                    f16* drow = V + (size_t)(b * NCH + chx) * HW + pixb;
                    f16v8 o0, o1;
                    #pragma unroll
                    for (int e = 0; e < 8; ++e) { o0[e] = (f16)res[c][e]; o1[e] = (f16)res[c][8+e]; }
                    *(f16v8*)(drow) = o0;
                    *(f16v8*)(drow + 8) = o1;
                }
            }
        }
        if (g < NGRP) __syncthreads();
    }
}

// ---- fused: vertical box + horizontal box + q combine  (V -> q planes) -----
__global__ __launch_bounds__(512, 2) void fused_q_k(const f16* __restrict__ V,
                                                    const float* __restrict__ Refs,
                                                    f16* __restrict__ Q) {
    __shared__ float lds[16 * RSTR];
    int bl = blockIdx.y;
    int b = bl / LL, l = bl - b * LL;
    int strip = blockIdx.x;
    int y0s = (strip * HH) / NSTRIP;
    int yend = ((strip + 1) * HH) / NSTRIP;
    bool prod = (threadIdx.x < 256);

    int pch = threadIdx.x >> 6;
    int cx = (threadIdx.x & 63) * 8;
    int chsel = (pch == 0) ? l : (LL + (pch - 1) * LL + l);
    const f16* pu = V + (size_t)(b * NCH + chsel) * HW + cx;
    float* ldsrow0 = lds + pch * WROW;
    int ws0 = swz(cx + 24);
    int ws1 = swz(cx + 28);
    float va[8];
    #pragma unroll
    for (int i = 0; i < 8; ++i) va[i] = 0.f;

    zero_pads(lds);

    if (prod) {
        int lo = y0s - RR - 1; if (lo < 0) lo = 0;
        warmup(pu, va, lo, y0s + RR - 1);
        produce8(pu, ldsrow0, va, y0s, yend, 0, ws0, ws1);
    }
    __syncthreads();

    int u = threadIdx.x - 256;
    int r = u >> 5, i = u & 31;
    int x0 = i << 4;

    for (int g = 1; g <= NGRP; ++g) {
        if (prod) {
            if (g < NGRP) produce8(pu, ldsrow0, va, y0s + g * 8, yend, g & 1, ws0, ws1);
        } else {
            int gc = g - 1;
            int row = y0s + gc * 8 + r;
            if (row < yend) {
                float res[4][16];
                const float* rbase = lds + (size_t)((gc & 1) * 8 + r) * RSTR;
                #pragma unroll
                for (int c = 0; c < 4; ++c) {
                    float raw[64];
                    load_raw_lds(rbase + c * WROW, x0, raw);
                    slide16(raw, res[c]);
                }
                size_t pixb = (size_t)row * WW + x0;
                f16* qrow = Q + (size_t)(b * LL + l) * HW + pixb;
                f16 tmpo[16];
                #pragma unroll
                for (int gq = 0; gq < 4; ++gq) {
                    float4 i0 = *(const float4*)(Refs + ((size_t)b * 3 + 0) * HW + pixb + 4 * gq);
                    float4 i1 = *(const float4*)(Refs + ((size_t)b * 3 + 1) * HW + pixb + 4 * gq);
                    float4 i2 = *(const float4*)(Refs + ((size_t)b * 3 + 2) * HW + pixb + 4 * gq);
                    float ic0[4] = {i0.x, i0.y, i0.z, i0.w};
                    float ic1[4] = {i1.x, i1.y, i1.z, i1.w};
                    float ic2[4] = {i2.x, i2.y, i2.z, i2.w};
                    #pragma unroll
                    for (int e = 0; e < 4; ++e) {
                        int k = 4 * gq + e;
                        float nrm = nrminv(x0 + k, row);
                        float q = (res[0][k] + res[1][k] * ic0[e] + res[2][k] * ic1[e]
                                   + res[3][k] * ic2[e]) * nrm;
                        tmpo[k] = (f16)q;
                    }
                }
                f16v8 o0, o1;
                #pragma unroll
                for (int e = 0; e < 8; ++e) { o0[e] = tmpo[e]; o1[e] = tmpo[8+e]; }
                *(f16v8*)(qrow) = o0;
                *(f16v8*)(qrow + 8) = o1;
            }
        }
        if (g < NGRP) __syncthreads();
    }
}

// ---- products: I and I*I into 9-plane/b fp32 compact buffer ----------------
__global__ __launch_bounds__(256) void prod_k(float* __restrict__ Pf,
                                              const float* __restrict__ Refs) {
    int idx = blockIdx.x * 256 + threadIdx.x;
    int b = idx >> 18, pix = idx & (HW - 1);
    float I0 = Refs[((size_t)b * 3 + 0) * HW + pix];
    float I1 = Refs[((size_t)b * 3 + 1) * HW + pix];
    float I2 = Refs[((size_t)b * 3 + 2) * HW + pix];
    size_t base = (size_t)b * 9 * HW + pix;
    Pf[base + (size_t)0 * HW] = I0;
    Pf[base + (size_t)1 * HW] = I1;
    Pf[base + (size_t)2 * HW] = I2;
    Pf[base + (size_t)3 * HW] = I0 * I0;
    Pf[base + (size_t)4 * HW] = I0 * I1;
    Pf[base + (size_t)5 * HW] = I0 * I2;
    Pf[base + (size_t)6 * HW] = I1 * I1;
    Pf[base + (size_t)7 * HW] = I1 * I2;
    Pf[base + (size_t)8 * HW] = I2 * I2;
}

// ---- prep: boxed(I,II) fp32 -> Ainv (6 planes), mI (3 planes) --------------
__global__ __launch_bounds__(256) void prep_k(const float* __restrict__ Bf,
                                              float* __restrict__ Ainv, float* __restrict__ mI,
                                              const float* __restrict__ epsp) {
    int idx = blockIdx.x * 256 + threadIdx.x;
    int b = idx >> 18, pix = idx & (HW - 1);
    int x = pix & (WW - 1), y = pix >> 9;
    float nrm = nrminv(x, y);
    float eps = epsp[0];
    size_t base = (size_t)b * 9 * HW + pix;
    float m0 = Bf[base + (size_t)0 * HW] * nrm;
    float m1 = Bf[base + (size_t)1 * HW] * nrm;
    float m2 = Bf[base + (size_t)2 * HW] * nrm;
    float v00 = Bf[base + (size_t)3 * HW] * nrm - m0 * m0 + eps;
    float v01 = Bf[base + (size_t)4 * HW] * nrm - m0 * m1;
    float v02 = Bf[base + (size_t)5 * HW] * nrm - m0 * m2;
    float v11 = Bf[base + (size_t)6 * HW] * nrm - m1 * m1 + eps;
    float v12 = Bf[base + (size_t)7 * HW] * nrm - m1 * m2;
    float v22 = Bf[base + (size_t)8 * HW] * nrm - m2 * m2 + eps;
    float c00 = v11 * v22 - v12 * v12;
    float c01 = v02 * v12 - v01 * v22;
    float c02 = v01 * v12 - v02 * v11;
    float c11 = v00 * v22 - v02 * v02;
    float c12 = v01 * v02 - v00 * v12;
    float c22 = v00 * v11 - v01 * v01;
    float det = v00 * c00 + v01 * c01 + v02 * c02;
    float id = 1.0f / det;
    size_t ab = (size_t)b * 6 * HW + pix;
    Ainv[ab + (size_t)0 * HW] = c00 * id;
    Ainv[ab + (size_t)1 * HW] = c01 * id;
    Ainv[ab + (size_t)2 * HW] = c02 * id;
    Ainv[ab + (size_t)3 * HW] = c11 * id;
    Ainv[ab + (size_t)4 * HW] = c12 * id;
    Ainv[ab + (size_t)5 * HW] = c22 * id;
    size_t mb = (size_t)b * 3 * HW + pix;
    mI[mb]                  = m0;
    mI[mb + (size_t)HW]     = m1;
    mI[mb + (size_t)2 * HW] = m2;
}

// ---- fused: E=E0+q, Q=softmax(-E), p=W.Q, Ip (2 px/thread) -----------------
// mode 0: Q0 from E0 only; 1: mid; 2: last (fp32 Q -> out)
__global__ __launch_bounds__(256) void e_k(const f16* __restrict__ Q,
                                           f16* __restrict__ pout,
                                           const float* __restrict__ E0,
                                           const float* __restrict__ Refs,
                                           const float* __restrict__ Wf,
                                           float* __restrict__ out, int mode) {
    int idx = blockIdx.x * 256 + threadIdx.x;
    int b = idx >> 17;
    int pix = (idx & (HW / 2 - 1)) * 2;
    size_t base  = (size_t)b * NCH * HW + pix;
    size_t ebase = (size_t)b * LL * HW + pix;
    float2 Ic0 = *(const float2*)(Refs + ((size_t)b * 3 + 0) * HW + pix);
    float2 Ic1 = *(const float2*)(Refs + ((size_t)b * 3 + 1) * HW + pix);
    float2 Ic2 = *(const float2*)(Refs + ((size_t)b * 3 + 2) * HW + pix);
    float Ev0[LL], Ev1[LL];
    float m0 = -1e30f, m1 = -1e30f;
    #pragma unroll
    for (int l = 0; l < LL; ++l) {
        float2 e0 = *(const float2*)(E0 + ebase + (size_t)l * HW);
        float v0 = e0.x, v1 = e0.y;
        if (mode != 0) {
            f16v2 qv = *(const f16v2*)(Q + ebase + (size_t)l * HW);
            v0 += (float)qv.x; v1 += (float)qv.y;
        }
        Ev0[l] = -v0; Ev1[l] = -v1;
        m0 = fmaxf(m0, Ev0[l]); m1 = fmaxf(m1, Ev1[l]);
    }
    float s0 = 0.f, s1 = 0.f;
    #pragma unroll
    for (int l = 0; l < LL; ++l) {
        Ev0[l] = __expf(Ev0[l] - m0); s0 += Ev0[l];
        Ev1[l] = __expf(Ev1[l] - m1); s1 += Ev1[l];
    }
    float i0 = 1.0f / s0, i1 = 1.0f / s1;
    if (mode == 2) {
        #pragma unroll
        for (int l = 0; l < LL; ++l) {
            float2 o; o.x = Ev0[l] * i0; o.y = Ev1[l] * i1;
            *(float2*)(out + ebase + (size_t)l * HW) = o;
        }
    } else {
        #pragma unroll
        for (int l = 0; l < LL; ++l) { Ev0[l] *= i0; Ev1[l] *= i1; }
        #pragma unroll
        for (int l = 0; l < LL; ++l) {
            float p0 = 0.f, p1 = 0.f;
            #pragma unroll
            for (int m = 0; m < LL; ++m) {
                float w = Wf[l * LL + m];
                p0 += w * Ev0[m]; p1 += w * Ev1[m];
            }
            f16v2 o;
            o.x = (f16)p0; o.y = (f16)p1;
            *(f16v2*)(pout + base + (size_t)l * HW) = o;
            o.x = (f16)(p0 * Ic0.x); o.y = (f16)(p1 * Ic0.y);
            *(f16v2*)(pout + base + (size_t)(LL + 0*LL + l) * HW) = o;
            o.x = (f16)(p0 * Ic1.x); o.y = (f16)(p1 * Ic1.y);
            *(f16v2*)(pout + base + (size_t)(LL + 1*LL + l) * HW) = o;
            o.x = (f16)(p0 * Ic2.x); o.y = (f16)(p1 * Ic2.y);
            *(f16v2*)(pout + base + (size_t)(LL + 2*LL + l) * HW) = o;
        }
    }
}

// ---- host ------------------------------------------------------------------
extern "C" void kernel_launch(void* const* d_in, const int* in_sizes, int n_in,
                              void* d_out, int out_size, void* d_ws, size_t ws_size,
                              hipStream_t stream) {
    const float* E0   = (const float*)d_in[0];
    const float* Refs = (const float*)d_in[1];
    const float* Wmu  = (const float*)d_in[2];
    const float* epsp = (const float*)d_in[3];
    float* out = (float*)d_out;

    size_t Ub = (size_t)BB * NCH * HW * 2;   // 84 MB fp16
    size_t Ab = (size_t)BB * 6 * HW * 4;     // 12 MB fp32
    size_t Mb = (size_t)BB * 3 * HW * 4;     // 6 MB fp32
    char* ws = (char*)d_ws;
    f16*   U    = (f16*)ws;
    f16*   V    = (f16*)(ws + Ub);           // loop: holds b,a planes (solve out)
    float* Ainv = (float*)(ws + 2 * Ub);
    float* mI   = (float*)(ws + 2 * Ub + Ab);
    f16*   Qb   = (f16*)(ws + 2 * Ub + Ab + Mb);  // 21 fp16 q planes x BB
    float* Uf   = (float*)U;                 // init fp32 alias (9 planes/b)
    float* Vf   = (float*)V;

    int nblk = (BB * HW) / 256;
    // init: I, I*I -> 2D box (fp32) -> Ainv, mI
    prod_k<<<nblk, 256, 0, stream>>>(Uf, Refs);
    vboxf_k<<<dim3(HH / VSEG, BB * 9), 128, 0, stream>>>(Uf, Vf);
    hboxf_k<<<dim3(HH / 8, BB * 9), 256, 0, stream>>>(Vf, Uf);
    prep_k<<<nblk, 256, 0, stream>>>(Uf, Ainv, mI, epsp);
    // Q0 -> p, Ip into U (mode 0 reads no Q)
    e_k<<<(BB * HW / 2) / 256, 256, 0, stream>>>(Qb, U, E0, Refs, Wmu, out, 0);

    for (int t = 1; t <= 5; ++t) {
        fused_solve_k<<<dim3(NSTRIP, BB * LL), 512, 0, stream>>>(U, V, Ainv, mI);
        fused_q_k<<<dim3(NSTRIP, BB * LL), 512, 0, stream>>>(V, Refs, Qb);
        e_k<<<(BB * HW / 2) / 256, 256, 0, stream>>>(Qb, U, E0, Refs, Wmu, out,
                                                     t == 5 ? 2 : 1);
    }
}

// Round 12
// 1164.905 us; speedup vs baseline: 2.4025x; 1.0051x over previous
//
#include <hip/hip_runtime.h>
#include <hip/hip_bf16.h>

typedef _Float16 f16;
typedef _Float16 f16v2 __attribute__((ext_vector_type(2)));
typedef _Float16 f16v4 __attribute__((ext_vector_type(4)));
typedef _Float16 f16v8 __attribute__((ext_vector_type(8)));

#define BB   2
#define LL   21
#define HH   512
#define WW   512
#define RR   20
#define NCH  84            // planes per batch: p(21), Ic*p(63); later b,a
#define HW   (HH*WW)
#define VSEG 64            // rows per strip, fp32 init vbox

// fused-kernel LDS ring geometry (f32 vertical sums, XOR-swizzled; round-4 verified)
#define WROW 576           // padded row: x_s in [0,576): 24 left pad, 512 data, 40 right pad
#define RSTR 2320          // ring-row stride in words: 4*576 + 16 (rotates banks per row)
#define NSTRIP 6
#define NGRP 11            // ceil(max strip rows (86) / 8)

__device__ __forceinline__ float nrminv(int x, int y) {
    int cx = min(x + RR, WW - 1) - max(x - RR, 0) + 1;
    int cy = min(y + RR, HH - 1) - max(y - RR, 0) + 1;
    return 1.0f / (float)(cx * cy);
}

// involution on word indices; consistent for aligned float4 (swz(w+i)=swz(w)+i, i<4, w%4==0)
__device__ __forceinline__ int swz(int w) { return w ^ ((w >> 3) & 0x1C); }

// ---- vertical box fp32 (init only): 4 cols/thread --------------------------
__global__ __launch_bounds__(128) void vboxf_k(const float* __restrict__ src,
                                               float* __restrict__ dst) {
    int pp = blockIdx.y;
    int y0 = blockIdx.x * VSEG;
    const float* s = src + (size_t)pp * HW + threadIdx.x * 4;
    float* d = dst + (size_t)pp * HW + threadIdx.x * 4;
    float s0 = 0.f, s1 = 0.f, s2 = 0.f, s3 = 0.f;
    int lo = y0 - RR; if (lo < 0) lo = 0;
    int hi = y0 + RR;
    for (int yy = lo; yy <= hi; ++yy) {
        float4 v = *(const float4*)(s + (size_t)yy * WW);
        s0 += v.x; s1 += v.y; s2 += v.z; s3 += v.w;
    }
    { float4 o = {s0, s1, s2, s3}; *(float4*)(d + (size_t)y0 * WW) = o; }
    #pragma unroll 4
    for (int y = y0 + 1; y < y0 + VSEG; ++y) {
        int ya = y + RR, ys = y - RR - 1;
        if (ya < HH) {
            float4 v = *(const float4*)(s + (size_t)ya * WW);
            s0 += v.x; s1 += v.y; s2 += v.z; s3 += v.w;
        }
        if (ys >= 0) {
            float4 v = *(const float4*)(s + (size_t)ys * WW);
            s0 -= v.x; s1 -= v.y; s2 -= v.z; s3 -= v.w;
        }
        float4 o = {s0, s1, s2, s3};
        *(float4*)(d + (size_t)y * WW) = o;
    }
}

// ---- horizontal window helpers ---------------------------------------------
template <typename T, typename V4>
__device__ __forceinline__ void load_win16(const T* __restrict__ srow, int x0,
                                           float* __restrict__ raw) {
    #pragma unroll
    for (int c = 0; c < 15; ++c) {
        int st = x0 - 24 + 4 * c;
        if (st >= 0 && st < WW) {
            V4 v = *(const V4*)(srow + st);
            raw[4*c+0] = (float)v.x; raw[4*c+1] = (float)v.y;
            raw[4*c+2] = (float)v.z; raw[4*c+3] = (float)v.w;
        } else {
            raw[4*c+0] = 0.f; raw[4*c+1] = 0.f; raw[4*c+2] = 0.f; raw[4*c+3] = 0.f;
        }
    }
}
__device__ __forceinline__ void slide16(const float* __restrict__ raw,
                                        float* __restrict__ res) {
    float sum = 0.f;
    #pragma unroll
    for (int j = 4; j <= 44; ++j) sum += raw[j];   // [x0-20, x0+20]
    res[0] = sum;
    #pragma unroll
    for (int k = 1; k < 16; ++k) { sum += raw[k+44] - raw[k+3]; res[k] = sum; }
}

// ---- plain horizontal box (init, fp32): 16 px/thread -----------------------
__global__ __launch_bounds__(256) void hboxf_k(const float* __restrict__ src,
                                               float* __restrict__ dst) {
    int pp = blockIdx.y;
    int row = blockIdx.x * 8 + (threadIdx.x >> 5);
    int x0 = (threadIdx.x & 31) << 4;
    const float* srow = src + (size_t)pp * HW + (size_t)row * WW;
    float raw[60], res[16];
    load_win16<float, float4>(srow, x0, raw);
    slide16(raw, res);
    float* drow = dst + (size_t)pp * HW + (size_t)row * WW + x0;
    #pragma unroll
    for (int g = 0; g < 4; ++g) {
        float4 o = {res[4*g], res[4*g+1], res[4*g+2], res[4*g+3]};
        *(float4*)(drow + 4*g) = o;
    }
}

// ---- fused 2D box: producer (vertical running sums -> f32 LDS ring) --------
// BATCHED: all 16 independent row-loads of a group issue first, then the
// serial running-sum adds. (Needs VGPR headroom — see launch_bounds note.)
__device__ __forceinline__ void produce8(const f16* __restrict__ pu,
                                         float* __restrict__ ldsrow0,
                                         float* __restrict__ va,
                                         int gy, int yend, int buf,
                                         int ws0, int ws1) {
    f16v8 ra[8], rb[8];
    #pragma unroll
    for (int k = 0; k < 8; ++k) {
        int y = gy + k;
        if (y < yend) {
            int ya = y + RR;
            if (ya < HH) ra[k] = *(const f16v8*)(pu + (size_t)ya * WW);
            int yb = y - RR - 1;
            if (yb >= 0) rb[k] = *(const f16v8*)(pu + (size_t)yb * WW);
        }
    }
    #pragma unroll
    for (int k = 0; k < 8; ++k) {
        int y = gy + k;
        if (y < yend) {
            int ya = y + RR;
            if (ya < HH) {
                #pragma unroll
                for (int i = 0; i < 8; ++i) va[i] += (float)ra[k][i];
            }
            int yb = y - RR - 1;
            if (yb >= 0) {
                #pragma unroll
                for (int i = 0; i < 8; ++i) va[i] -= (float)rb[k][i];
            }
            float* dst = ldsrow0 + (size_t)(buf * 8 + k) * RSTR;
            float4 a = {va[0], va[1], va[2], va[3]};
            float4 b4 = {va[4], va[5], va[6], va[7]};
            *(float4*)(dst + ws0) = a;
            *(float4*)(dst + ws1) = b4;
        }
    }
}

// batched warm-up: accumulate rows [lo, hi] into va, loads batched 8 at a time
__device__ __forceinline__ void warmup(const f16* __restrict__ pu,
                                       float* __restrict__ va, int lo, int hi) {
    for (int y0c = lo; y0c <= hi; y0c += 8) {
        f16v8 r[8];
        #pragma unroll
        for (int k = 0; k < 8; ++k)
            if (y0c + k <= hi) r[k] = *(const f16v8*)(pu + (size_t)(y0c + k) * WW);
        #pragma unroll
        for (int k = 0; k < 8; ++k)
            if (y0c + k <= hi) {
                #pragma unroll
                for (int i = 0; i < 8; ++i) va[i] += (float)r[k][i];
            }
    }
}

// consumer raw-window load from swizzled LDS ring row
__device__ __forceinline__ void load_raw_lds(const float* __restrict__ base,
                                             int x0, float* __restrict__ raw) {
    #pragma unroll
    for (int k = 0; k < 16; ++k) {
        int w = x0 + 4 * k;
        float4 v = *(const float4*)(base + swz(w));
        raw[4*k+0] = v.x; raw[4*k+1] = v.y; raw[4*k+2] = v.z; raw[4*k+3] = v.w;
    }
}

// zero the pad columns (x_s in [0,24) and [536,576)) of all 16 ring rows x 4 ch
__device__ __forceinline__ void zero_pads(float* __restrict__ lds) {
    for (int p = threadIdx.x; p < 16 * 4 * 64; p += 512) {
        int ringrow = p >> 8;
        int rem = p & 255;
        int chp = rem >> 6, j = rem & 63;
        int w = (j < 24) ? j : (512 + j);
        lds[(size_t)ringrow * RSTR + chp * WROW + swz(w)] = 0.f;
    }
}

// ---- fused: vertical box + horizontal box + 3x3 solve  (U -> V as b,a) -----
// launch_bounds (512, 1): LDS (145 KB) already caps at 1 block/CU = 2 waves/
// SIMD, so raising the VGPR budget costs no occupancy — it removes the
// scratch spill of the batched producer arrays (round-11: WRITE 86->264 MB).
__global__ __launch_bounds__(512, 1) void fused_solve_k(const f16* __restrict__ U,
                                                        f16* __restrict__ V,
                                                        const float* __restrict__ Ainv,
                                                        const float* __restrict__ mI) {
    __shared__ float lds[16 * RSTR];     // 145 KB
    int bl = blockIdx.y;
    int b = bl / LL, l = bl - b * LL;
    int strip = blockIdx.x;
    int y0s = (strip * HH) / NSTRIP;
    int yend = ((strip + 1) * HH) / NSTRIP;
    bool prod = (threadIdx.x < 256);

    int pch = threadIdx.x >> 6;          // producer channel 0..3
    int cx = (threadIdx.x & 63) * 8;
    int chsel = (pch == 0) ? l : (LL + (pch - 1) * LL + l);
    const f16* pu = U + (size_t)(b * NCH + chsel) * HW + cx;
    float* ldsrow0 = lds + pch * WROW;
    int ws0 = swz(cx + 24);
    int ws1 = swz(cx + 28);
    float va[8];
    #pragma unroll
    for (int i = 0; i < 8; ++i) va[i] = 0.f;

    zero_pads(lds);

    if (prod) {
        int lo = y0s - RR - 1; if (lo < 0) lo = 0;
        warmup(pu, va, lo, y0s + RR - 1);
        produce8(pu, ldsrow0, va, y0s, yend, 0, ws0, ws1);
    }
    __syncthreads();

    int u = threadIdx.x - 256;
    int r = u >> 5, i = u & 31;          // consumer: row slot, px group
    int x0 = i << 4;

    for (int g = 1; g <= NGRP; ++g) {
        if (prod) {
            if (g < NGRP) produce8(pu, ldsrow0, va, y0s + g * 8, yend, g & 1, ws0, ws1);
        } else {
            int gc = g - 1;
            int row = y0s + gc * 8 + r;
            if (row < yend) {
                float res[4][16];
                const float* rbase = lds + (size_t)((gc & 1) * 8 + r) * RSTR;
                #pragma unroll
                for (int c = 0; c < 4; ++c) {
                    float raw[64];
                    load_raw_lds(rbase + c * WROW, x0, raw);
                    slide16(raw, res[c]);
                }
                size_t pixb = (size_t)row * WW + x0;
                size_t ab = (size_t)b * 6 * HW + pixb;
                size_t mb = (size_t)b * 3 * HW + pixb;
                #pragma unroll
                for (int gq = 0; gq < 4; ++gq) {
                    float iv[6][4], mi[3][4];
                    #pragma unroll
                    for (int j = 0; j < 6; ++j) {
                        float4 v = *(const float4*)(Ainv + ab + (size_t)j * HW + 4 * gq);
                        iv[j][0] = v.x; iv[j][1] = v.y; iv[j][2] = v.z; iv[j][3] = v.w;
                    }
                    #pragma unroll
                    for (int j = 0; j < 3; ++j) {
                        float4 v = *(const float4*)(mI + mb + (size_t)j * HW + 4 * gq);
                        mi[j][0] = v.x; mi[j][1] = v.y; mi[j][2] = v.z; mi[j][3] = v.w;
                    }
                    #pragma unroll
                    for (int e = 0; e < 4; ++e) {
                        int k = 4 * gq + e;
                        float nrm = nrminv(x0 + k, row);
                        float mp   = res[0][k] * nrm;
                        float cov0 = res[1][k] * nrm - mi[0][e] * mp;
                        float cov1 = res[2][k] * nrm - mi[1][e] * mp;
                        float cov2 = res[3][k] * nrm - mi[2][e] * mp;
                        float a0 = iv[0][e] * cov0 + iv[1][e] * cov1 + iv[2][e] * cov2;
                        float a1 = iv[1][e] * cov0 + iv[3][e] * cov1 + iv[4][e] * cov2;
                        float a2 = iv[2][e] * cov0 + iv[4][e] * cov1 + iv[5][e] * cov2;
                        float bb = mp - (a0 * mi[0][e] + a1 * mi[1][e] + a2 * mi[2][e]);
                        res[0][k] = bb; res[1][k] = a0; res[2][k] = a1; res[3][k] = a2;
                    }
                }
                #pragma unroll
                for (int c = 0; c < 4; ++c) {
                    int chx = (c == 0) ? l : (LL + (c - 1) * LL + l);
                    f16* drow = V + (size_t)(b * NCH + chx) * HW + pixb;
                    f16v8 o0, o1;
                    #pragma unroll
                    for (int e = 0; e < 8; ++e) { o0[e] = (f16)res[c][e]; o1[e] = (f16)res[c][8+e]; }
                    *(f16v8*)(drow) = o0;
                    *(f16v8*)(drow + 8) = o1;
                }
            }
        }
        if (g < NGRP) __syncthreads();
    }
}

// ---- fused: vertical box + horizontal box + q combine  (V -> q planes) -----
__global__ __launch_bounds__(512, 2) void fused_q_k(const f16* __restrict__ V,
                                                    const float* __restrict__ Refs,
                                                    f16* __restrict__ Q) {
    __shared__ float lds[16 * RSTR];
    int bl = blockIdx.y;
    int b = bl / LL, l = bl - b * LL;
    int strip = blockIdx.x;
    int y0s = (strip * HH) / NSTRIP;
    int yend = ((strip + 1) * HH) / NSTRIP;
    bool prod = (threadIdx.x < 256);

    int pch = threadIdx.x >> 6;
    int cx = (threadIdx.x & 63) * 8;
    int chsel = (pch == 0) ? l : (LL + (pch - 1) * LL + l);
    const f16* pu = V + (size_t)(b * NCH + chsel) * HW + cx;
    float* ldsrow0 = lds + pch * WROW;
    int ws0 = swz(cx + 24);
    int ws1 = swz(cx + 28);
    float va[8];
    #pragma unroll
    for (int i = 0; i < 8; ++i) va[i] = 0.f;

    zero_pads(lds);

    if (prod) {
        int lo = y0s - RR - 1; if (lo < 0) lo = 0;
        warmup(pu, va, lo, y0s + RR - 1);
        produce8(pu, ldsrow0, va, y0s, yend, 0, ws0, ws1);
    }
    __syncthreads();

    int u = threadIdx.x - 256;
    int r = u >> 5, i = u & 31;
    int x0 = i << 4;

    for (int g = 1; g <= NGRP; ++g) {
        if (prod) {
            if (g < NGRP) produce8(pu, ldsrow0, va, y0s + g * 8, yend, g & 1, ws0, ws1);
        } else {
            int gc = g - 1;
            int row = y0s + gc * 8 + r;
            if (row < yend) {
                float res[4][16];
                const float* rbase = lds + (size_t)((gc & 1) * 8 + r) * RSTR;
                #pragma unroll
                for (int c = 0; c < 4; ++c) {
                    float raw[64];
                    load_raw_lds(rbase + c * WROW, x0, raw);
                    slide16(raw, res[c]);
                }
                size_t pixb = (size_t)row * WW + x0;
                f16* qrow = Q + (size_t)(b * LL + l) * HW + pixb;
                f16 tmpo[16];
                #pragma unroll
                for (int gq = 0; gq < 4; ++gq) {
                    float4 i0 = *(const float4*)(Refs + ((size_t)b * 3 + 0) * HW + pixb + 4 * gq);
                    float4 i1 = *(const float4*)(Refs + ((size_t)b * 3 + 1) * HW + pixb + 4 * gq);
                    float4 i2 = *(const float4*)(Refs + ((size_t)b * 3 + 2) * HW + pixb + 4 * gq);
                    float ic0[4] = {i0.x, i0.y, i0.z, i0.w};
                    float ic1[4] = {i1.x, i1.y, i1.z, i1.w};
                    float ic2[4] = {i2.x, i2.y, i2.z, i2.w};
                    #pragma unroll
                    for (int e = 0; e < 4; ++e) {
                        int k = 4 * gq + e;
                        float nrm = nrminv(x0 + k, row);
                        float q = (res[0][k] + res[1][k] * ic0[e] + res[2][k] * ic1[e]
                                   + res[3][k] * ic2[e]) * nrm;
                        tmpo[k] = (f16)q;
                    }
                }
                f16v8 o0, o1;
                #pragma unroll
                for (int e = 0; e < 8; ++e) { o0[e] = tmpo[e]; o1[e] = tmpo[8+e]; }
                *(f16v8*)(qrow) = o0;
                *(f16v8*)(qrow + 8) = o1;
            }
        }
        if (g < NGRP) __syncthreads();
    }
}

// ---- products: I and I*I into 9-plane/b fp32 compact buffer ----------------
__global__ __launch_bounds__(256) void prod_k(float* __restrict__ Pf,
                                              const float* __restrict__ Refs) {
    int idx = blockIdx.x * 256 + threadIdx.x;
    int b = idx >> 18, pix = idx & (HW - 1);
    float I0 = Refs[((size_t)b * 3 + 0) * HW + pix];
    float I1 = Refs[((size_t)b * 3 + 1) * HW + pix];
    float I2 = Refs[((size_t)b * 3 + 2) * HW + pix];
    size_t base = (size_t)b * 9 * HW + pix;
    Pf[base + (size_t)0 * HW] = I0;
    Pf[base + (size_t)1 * HW] = I1;
    Pf[base + (size_t)2 * HW] = I2;
    Pf[base + (size_t)3 * HW] = I0 * I0;
    Pf[base + (size_t)4 * HW] = I0 * I1;
    Pf[base + (size_t)5 * HW] = I0 * I2;
    Pf[base + (size_t)6 * HW] = I1 * I1;
    Pf[base + (size_t)7 * HW] = I1 * I2;
    Pf[base + (size_t)8 * HW] = I2 * I2;
}

// ---- prep: boxed(I,II) fp32 -> Ainv (6 planes), mI (3 planes) --------------
__global__ __launch_bounds__(256) void prep_k(const float* __restrict__ Bf,
                                              float* __restrict__ Ainv, float* __restrict__ mI,
                                              const float* __restrict__ epsp) {
    int idx = blockIdx.x * 256 + threadIdx.x;
    int b = idx >> 18, pix = idx & (HW - 1);
    int x = pix & (WW - 1), y = pix >> 9;
    float nrm = nrminv(x, y);
    float eps = epsp[0];
    size_t base = (size_t)b * 9 * HW + pix;
    float m0 = Bf[base + (size_t)0 * HW] * nrm;
    float m1 = Bf[base + (size_t)1 * HW] * nrm;
    float m2 = Bf[base + (size_t)2 * HW] * nrm;
    float v00 = Bf[base + (size_t)3 * HW] * nrm - m0 * m0 + eps;
    float v01 = Bf[base + (size_t)4 * HW] * nrm - m0 * m1;
    float v02 = Bf[base + (size_t)5 * HW] * nrm - m0 * m2;
    float v11 = Bf[base + (size_t)6 * HW] * nrm - m1 * m1 + eps;
    float v12 = Bf[base + (size_t)7 * HW] * nrm - m1 * m2;
    float v22 = Bf[base + (size_t)8 * HW] * nrm - m2 * m2 + eps;
    float c00 = v11 * v22 - v12 * v12;
    float c01 = v02 * v12 - v01 * v22;
    float c02 = v01 * v12 - v02 * v11;
    float c11 = v00 * v22 - v02 * v02;
    float c12 = v01 * v02 - v00 * v12;
    float c22 = v00 * v11 - v01 * v01;
    float det = v00 * c00 + v01 * c01 + v02 * c02;
    float id = 1.0f / det;
    size_t ab = (size_t)b * 6 * HW + pix;
    Ainv[ab + (size_t)0 * HW] = c00 * id;
    Ainv[ab + (size_t)1 * HW] = c01 * id;
    Ainv[ab + (size_t)2 * HW] = c02 * id;
    Ainv[ab + (size_t)3 * HW] = c11 * id;
    Ainv[ab + (size_t)4 * HW] = c12 * id;
    Ainv[ab + (size_t)5 * HW] = c22 * id;
    size_t mb = (size_t)b * 3 * HW + pix;
    mI[mb]                  = m0;
    mI[mb + (size_t)HW]     = m1;
    mI[mb + (size_t)2 * HW] = m2;
}

// ---- fused: E=E0+q, Q=softmax(-E), p=W.Q, Ip (2 px/thread) -----------------
// mode 0: Q0 from E0 only; 1: mid; 2: last (fp32 Q -> out)
__global__ __launch_bounds__(256) void e_k(const f16* __restrict__ Q,
                                           f16* __restrict__ pout,
                                           const float* __restrict__ E0,
                                           const float* __restrict__ Refs,
                                           const float* __restrict__ Wf,
                                           float* __restrict__ out, int mode) {
    int idx = blockIdx.x * 256 + threadIdx.x;
    int b = idx >> 17;
    int pix = (idx & (HW / 2 - 1)) * 2;
    size_t base  = (size_t)b * NCH * HW + pix;
    size_t ebase = (size_t)b * LL * HW + pix;
    float2 Ic0 = *(const float2*)(Refs + ((size_t)b * 3 + 0) * HW + pix);
    float2 Ic1 = *(const float2*)(Refs + ((size_t)b * 3 + 1) * HW + pix);
    float2 Ic2 = *(const float2*)(Refs + ((size_t)b * 3 + 2) * HW + pix);
    float Ev0[LL], Ev1[LL];
    float m0 = -1e30f, m1 = -1e30f;
    #pragma unroll
    for (int l = 0; l < LL; ++l) {
        float2 e0 = *(const float2*)(E0 + ebase + (size_t)l * HW);
        float v0 = e0.x, v1 = e0.y;
        if (mode != 0) {
            f16v2 qv = *(const f16v2*)(Q + ebase + (size_t)l * HW);
            v0 += (float)qv.x; v1 += (float)qv.y;
        }
        Ev0[l] = -v0; Ev1[l] = -v1;
        m0 = fmaxf(m0, Ev0[l]); m1 = fmaxf(m1, Ev1[l]);
    }
    float s0 = 0.f, s1 = 0.f;
    #pragma unroll
    for (int l = 0; l < LL; ++l) {
        Ev0[l] = __expf(Ev0[l] - m0); s0 += Ev0[l];
        Ev1[l] = __expf(Ev1[l] - m1); s1 += Ev1[l];
    }
    float i0 = 1.0f / s0, i1 = 1.0f / s1;
    if (mode == 2) {
        #pragma unroll
        for (int l = 0; l < LL; ++l) {
            float2 o; o.x = Ev0[l] * i0; o.y = Ev1[l] * i1;
            *(float2*)(out + ebase + (size_t)l * HW) = o;
        }
    } else {
        #pragma unroll
        for (int l = 0; l < LL; ++l) { Ev0[l] *= i0; Ev1[l] *= i1; }
        #pragma unroll
        for (int l = 0; l < LL; ++l) {
            float p0 = 0.f, p1 = 0.f;
            #pragma unroll
            for (int m = 0; m < LL; ++m) {
                float w = Wf[l * LL + m];
                p0 += w * Ev0[m]; p1 += w * Ev1[m];
            }
            f16v2 o;
            o.x = (f16)p0; o.y = (f16)p1;
            *(f16v2*)(pout + base + (size_t)l * HW) = o;
            o.x = (f16)(p0 * Ic0.x); o.y = (f16)(p1 * Ic0.y);
            *(f16v2*)(pout + base + (size_t)(LL + 0*LL + l) * HW) = o;
            o.x = (f16)(p0 * Ic1.x); o.y = (f16)(p1 * Ic1.y);
            *(f16v2*)(pout + base + (size_t)(LL + 1*LL + l) * HW) = o;
            o.x = (f16)(p0 * Ic2.x); o.y = (f16)(p1 * Ic2.y);
            *(f16v2*)(pout + base + (size_t)(LL + 2*LL + l) * HW) = o;
        }
    }
}

// ---- host ------------------------------------------------------------------
extern "C" void kernel_launch(void* const* d_in, const int* in_sizes, int n_in,
                              void* d_out, int out_size, void* d_ws, size_t ws_size,
                              hipStream_t stream) {
    const float* E0   = (const float*)d_in[0];
    const float* Refs = (const float*)d_in[1];
    const float* Wmu  = (const float*)d_in[2];
    const float* epsp = (const float*)d_in[3];
    float* out = (float*)d_out;

    size_t Ub = (size_t)BB * NCH * HW * 2;   // 84 MB fp16
    size_t Ab = (size_t)BB * 6 * HW * 4;     // 12 MB fp32
    size_t Mb = (size_t)BB * 3 * HW * 4;     // 6 MB fp32
    char* ws = (char*)d_ws;
    f16*   U    = (f16*)ws;
    f16*   V    = (f16*)(ws + Ub);           // loop: holds b,a planes (solve out)
    float* Ainv = (float*)(ws + 2 * Ub);
    float* mI   = (float*)(ws + 2 * Ub + Ab);
    f16*   Qb   = (f16*)(ws + 2 * Ub + Ab + Mb);  // 21 fp16 q planes x BB
    float* Uf   = (float*)U;                 // init fp32 alias (9 planes/b)
    float* Vf   = (float*)V;

    int nblk = (BB * HW) / 256;
    // init: I, I*I -> 2D box (fp32) -> Ainv, mI
    prod_k<<<nblk, 256, 0, stream>>>(Uf, Refs);
    vboxf_k<<<dim3(HH / VSEG, BB * 9), 128, 0, stream>>>(Uf, Vf);
    hboxf_k<<<dim3(HH / 8, BB * 9), 256, 0, stream>>>(Vf, Uf);
    prep_k<<<nblk, 256, 0, stream>>>(Uf, Ainv, mI, epsp);
    // Q0 -> p, Ip into U (mode 0 reads no Q)
    e_k<<<(BB * HW / 2) / 256, 256, 0, stream>>>(Qb, U, E0, Refs, Wmu, out, 0);

    for (int t = 1; t <= 5; ++t) {
        fused_solve_k<<<dim3(NSTRIP, BB * LL), 512, 0, stream>>>(U, V, Ainv, mI);
        fused_q_k<<<dim3(NSTRIP, BB * LL), 512, 0, stream>>>(V, Refs, Qb);
        e_k<<<(BB * HW / 2) / 256, 256, 0, stream>>>(Qb, U, E0, Refs, Wmu, out,
                                                     t == 5 ? 2 : 1);
    }
}